// Round 17
// baseline (130.267 us; speedup 1.0000x reference)
//
#include <hip/hip_runtime.h>
#include <math.h>

// Problem constants (fixed by setup_inputs)
#define NWORDS 8192
#define LW     24
#define VOC    128
#define DIM    512
#define NH     8
#define DKH    64
#define GNAMES 2048
#define F2     256

// stage-1 fused output layout (floats): [EQ 65536 | EK 65536 | EV 65536 | WF 262144]
#define S1_LEN 458752

// =================== double-buffered 64x64 fp32 GEMM body ====================
// 256 threads, BK=16, 4x4 register tile, one barrier per K-step.
// K_ is used as lda, N_ as ldb only.
#define GEMM_BODY(A_, B_, K_, N_, m0_, n0_, kbeg_, kchunk_)                         \
  __shared__ float As[2][16][68];                                                   \
  __shared__ float Bs[2][16][68];                                                   \
  const int t = threadIdx.x, tx = t & 15, ty = t >> 4;                              \
  float acc[4][4] = {};                                                             \
  float ra[4], rb[4];                                                               \
  _Pragma("unroll")                                                                 \
  for (int i = 0; i < 4; ++i) { int idx = t + 256 * i;                              \
    ra[i] = A_[(size_t)(m0_ + (idx >> 4)) * K_ + kbeg_ + (idx & 15)]; }             \
  _Pragma("unroll")                                                                 \
  for (int i = 0; i < 4; ++i) { int idx = t + 256 * i;                              \
    rb[i] = B_[(size_t)(kbeg_ + (idx >> 6)) * N_ + n0_ + (idx & 63)]; }             \
  _Pragma("unroll")                                                                 \
  for (int i = 0; i < 4; ++i) { int idx = t + 256 * i; As[0][idx & 15][idx >> 4] = ra[i]; } \
  _Pragma("unroll")                                                                 \
  for (int i = 0; i < 4; ++i) { int idx = t + 256 * i; Bs[0][idx >> 6][idx & 63] = rb[i]; } \
  __syncthreads();                                                                  \
  int buf = 0;                                                                      \
  for (int k0 = kbeg_; k0 < kbeg_ + kchunk_; k0 += 16) {                            \
    const bool more = (k0 + 16 < kbeg_ + kchunk_);                                  \
    if (more) {                                                                     \
      _Pragma("unroll")                                                             \
      for (int i = 0; i < 4; ++i) { int idx = t + 256 * i;                          \
        ra[i] = A_[(size_t)(m0_ + (idx >> 4)) * K_ + (k0 + 16) + (idx & 15)]; }     \
      _Pragma("unroll")                                                             \
      for (int i = 0; i < 4; ++i) { int idx = t + 256 * i;                          \
        rb[i] = B_[(size_t)(k0 + 16 + (idx >> 6)) * N_ + n0_ + (idx & 63)]; }       \
    }                                                                               \
    _Pragma("unroll")                                                               \
    for (int k = 0; k < 16; ++k) {                                                  \
      float a[4], b[4];                                                             \
      _Pragma("unroll")                                                             \
      for (int i = 0; i < 4; ++i) a[i] = As[buf][k][ty * 4 + i];                    \
      _Pragma("unroll")                                                             \
      for (int j = 0; j < 4; ++j) b[j] = Bs[buf][k][tx * 4 + j];                    \
      _Pragma("unroll")                                                             \
      for (int i = 0; i < 4; ++i)                                                   \
        _Pragma("unroll")                                                           \
        for (int j = 0; j < 4; ++j) acc[i][j] += a[i] * b[j];                       \
    }                                                                               \
    if (more) {                                                                     \
      _Pragma("unroll")                                                             \
      for (int i = 0; i < 4; ++i) { int idx = t + 256 * i; As[buf ^ 1][idx & 15][idx >> 4] = ra[i]; } \
      _Pragma("unroll")                                                             \
      for (int i = 0; i < 4; ++i) { int idx = t + 256 * i; Bs[buf ^ 1][idx >> 6][idx & 63] = rb[i]; } \
      __syncthreads();                                                              \
      buf ^= 1;                                                                     \
    }                                                                               \
  }

// ---- stage-1 fused GEMM: EQ/EK/EV (128x512) + WF=Wo@W1 (512x512), all K=512 ----
// split-K=4, writes 4 planar partials P[s][S1_LEN]. Consumers fold the sum.
template<int NSPLIT>
__global__ __launch_bounds__(256) void k_stage1(const float* __restrict__ emb,
                                                const float* __restrict__ Wq,
                                                const float* __restrict__ Wk,
                                                const float* __restrict__ Wv,
                                                const float* __restrict__ Wo,
                                                const float* __restrict__ W1,
                                                float* __restrict__ P) {
  const int tid = blockIdx.x, s = blockIdx.y;
  const float *A, *B;
  int coff, m0, n0;
  if (tid < 48) {
    const int g = tid >> 4, mt = tid & 15;
    A = emb;
    B = (g == 0) ? Wq : ((g == 1) ? Wk : Wv);
    coff = g * 65536;
    m0 = (mt >> 3) * 64; n0 = (mt & 7) * 64;
  } else {
    const int id = tid - 48;
    A = Wo; B = W1; coff = 3 * 65536;
    m0 = (id >> 3) * 64; n0 = (id & 7) * 64;
  }
  const int kchunk = 512 / NSPLIT, kbeg = s * kchunk;
  GEMM_BODY(A, B, 512, 512, m0, n0, kbeg, kchunk)
  float* Cp = P + (size_t)s * S1_LEN + coff;
  #pragma unroll
  for (int i = 0; i < 4; ++i) {
    float4 v = make_float4(acc[i][0], acc[i][1], acc[i][2], acc[i][3]);
    *(float4*)&Cp[(size_t)(m0 + ty * 4 + i) * 512 + n0 + tx * 4] = v;
  }
}

// ---- fused tiled kernel: exp-table tiles + EVW tiles, reading RAW stage-1
// partials (4-way sum folded into the tile loads; the elementwise reduce
// kernel is eliminated).
//   blocks [0,32):  exp tile.  h=b>>2, mt=(b>>1)&1, nt=b&1. 64x64 of
//                   etab[c1][c2][h] = exp(0.125*dot(EQ_h[c1], EK_h[c2])),
//                   zeroed on pad rows/cols.
//   blocks [32,160): EVW tile. b2=b-32: h=b2>>4, mt=(b2>>3)&1, nt=b2&7.
//                   EVW[h*128+c][j] = sum_d EV[c][h*64+d]*WF[h*64+d][j].
__global__ __launch_bounds__(256) void k_tab_evw(const float* __restrict__ P,
                                                 float* __restrict__ etab,
                                                 float* __restrict__ EVW) {
  __shared__ float As[64][65];
  __shared__ float Bs[64][65];
  const int t = threadIdx.x, tx = t & 15, ty = t >> 4;
  const int b = blockIdx.x;

  if (b < 32) {
    const int h = b >> 2, mt = (b >> 1) & 1, nt = b & 1;
    const int m0 = mt * 64, n0 = nt * 64;
    #pragma unroll
    for (int i = 0; i < 16; ++i) {
      int idx = t + 256 * i;          // 0..4095
      int r = idx >> 6, d = idx & 63;
      size_t ao = (size_t)(m0 + r) * 512 + h * 64 + d;            // EQ row r
      As[d][r] = P[ao] + P[ao + S1_LEN] + P[ao + 2 * S1_LEN] + P[ao + 3 * S1_LEN];
      size_t bo = 65536 + (size_t)(n0 + r) * 512 + h * 64 + d;    // EK row r
      Bs[d][r] = P[bo] + P[bo + S1_LEN] + P[bo + 2 * S1_LEN] + P[bo + 3 * S1_LEN];
    }
    __syncthreads();
    float acc[4][4] = {};
    for (int d = 0; d < 64; ++d) {
      float a[4], bb[4];
      #pragma unroll
      for (int i = 0; i < 4; ++i) a[i] = As[d][ty * 4 + i];
      #pragma unroll
      for (int j = 0; j < 4; ++j) bb[j] = Bs[d][tx * 4 + j];
      #pragma unroll
      for (int i = 0; i < 4; ++i)
        #pragma unroll
        for (int j = 0; j < 4; ++j) acc[i][j] += a[i] * bb[j];
    }
    #pragma unroll
    for (int i = 0; i < 4; ++i) {
      int c1 = m0 + ty * 4 + i;
      #pragma unroll
      for (int j = 0; j < 4; ++j) {
        int c2 = n0 + tx * 4 + j;
        float e = (c1 != 0 && c2 != 0) ? __expf(acc[i][j] * 0.125f) : 0.f;
        etab[((size_t)c1 * VOC + c2) * NH + h] = e;
      }
    }
  } else {
    const int b2 = b - 32;
    const int h = b2 >> 4, mt = (b2 >> 3) & 1, nt = b2 & 7;
    const int m0 = mt * 64, n0 = nt * 64;
    #pragma unroll
    for (int i = 0; i < 16; ++i) {
      int idx = t + 256 * i;
      int r = idx >> 6, d = idx & 63;
      size_t ao = 131072 + (size_t)(m0 + r) * 512 + h * 64 + d;   // EV row r
      As[d][r] = P[ao] + P[ao + S1_LEN] + P[ao + 2 * S1_LEN] + P[ao + 3 * S1_LEN];
      size_t bo = 196608 + (size_t)(h * 64 + r) * 512 + n0 + d;   // WF row r, col d
      Bs[r][d] = P[bo] + P[bo + S1_LEN] + P[bo + 2 * S1_LEN] + P[bo + 3 * S1_LEN];
    }
    __syncthreads();
    float acc[4][4] = {};
    for (int d = 0; d < 64; ++d) {
      float a[4], bb[4];
      #pragma unroll
      for (int i = 0; i < 4; ++i) a[i] = As[d][ty * 4 + i];
      #pragma unroll
      for (int j = 0; j < 4; ++j) bb[j] = Bs[d][tx * 4 + j];
      #pragma unroll
      for (int i = 0; i < 4; ++i)
        #pragma unroll
        for (int j = 0; j < 4; ++j) acc[i][j] += a[i] * bb[j];
    }
    #pragma unroll
    for (int i = 0; i < 4; ++i) {
      int cg = m0 + ty * 4 + i;
      float4 v = make_float4(acc[i][0], acc[i][1], acc[i][2], acc[i][3]);
      *(float4*)&EVW[(size_t)(h * 128 + cg) * 512 + n0 + tx * 4] = v;
    }
  }
}

// ---- G = Wn @ EVW (K=1024) with 8-way INTERLEAVED split-K partial store ----
// P layout: float4 index ((m*128 + k4)*8 + s); tail sums 8 contiguous float4.
__global__ __launch_bounds__(256) void k_gemm_ilv(const float* __restrict__ A,
                                                  const float* __restrict__ B,
                                                  float* __restrict__ P,
                                                  int kchunk) {
  const int m0 = blockIdx.y * 64, n0 = blockIdx.x * 64;
  const int kbeg = blockIdx.z * kchunk;
  const int sz = blockIdx.z;
  GEMM_BODY(A, B, 1024, 512, m0, n0, kbeg, kchunk)
  float4* P4 = (float4*)P;
  #pragma unroll
  for (int i = 0; i < 4; ++i) {
    float4 v = make_float4(acc[i][0], acc[i][1], acc[i][2], acc[i][3]);
    P4[((size_t)(m0 + ty * 4 + i) * 128 + (n0 >> 2) + tx) * 8 + sz] = v;
  }
}

// ---- tail GEMM: A = tanh(sum of 8 interleaved partials), B = W2 ----
// A-fill per thread: one (m, k4-group) -> 8 contiguous float4 loads (128B),
// component-wise sum, 4 tanh, 4 LDS stores. split over gridDim.z (=4).
__global__ __launch_bounds__(256) void k_gemm_tail(const float* __restrict__ P,
                                                   const float* __restrict__ B,
                                                   float* __restrict__ C,
                                                   int kchunk) {
  const int N = 256, K = 512;
  __shared__ float As[2][16][68];
  __shared__ float Bs[2][16][68];
  const int t = threadIdx.x, tx = t & 15, ty = t >> 4;
  const int m0 = blockIdx.y * 64, n0 = blockIdx.x * 64;
  const int kbeg = blockIdx.z * kchunk;
  const float4* P4 = (const float4*)P;
  const int am = t >> 2, ak = t & 3;   // A map: 64 rows x 4 k4-groups
  float acc[4][4] = {};
  float4 ta;
  float rb[4];
#define TAIL_LOAD_A(kb)                                                   \
  {                                                                       \
    size_t b4 = ((size_t)(m0 + am) * 128 + ((kb) >> 2) + ak) * 8;         \
    float4 p0 = P4[b4 + 0], p1 = P4[b4 + 1], p2 = P4[b4 + 2], p3 = P4[b4 + 3]; \
    float4 p4 = P4[b4 + 4], p5 = P4[b4 + 5], p6 = P4[b4 + 6], p7 = P4[b4 + 7]; \
    ta.x = tanhf(p0.x + p1.x + p2.x + p3.x + p4.x + p5.x + p6.x + p7.x);  \
    ta.y = tanhf(p0.y + p1.y + p2.y + p3.y + p4.y + p5.y + p6.y + p7.y);  \
    ta.z = tanhf(p0.z + p1.z + p2.z + p3.z + p4.z + p5.z + p6.z + p7.z);  \
    ta.w = tanhf(p0.w + p1.w + p2.w + p3.w + p4.w + p5.w + p6.w + p7.w);  \
  }
#define TAIL_LOAD_B(kb)                                                   \
  _Pragma("unroll")                                                       \
  for (int i = 0; i < 4; ++i) { int idx = t + 256 * i;                    \
    rb[i] = B[(size_t)((kb) + (idx >> 6)) * N + n0 + (idx & 63)]; }
#define TAIL_STORE(bb)                                                    \
  { int kk = ak * 4;                                                      \
    As[bb][kk + 0][am] = ta.x; As[bb][kk + 1][am] = ta.y;                 \
    As[bb][kk + 2][am] = ta.z; As[bb][kk + 3][am] = ta.w; }               \
  _Pragma("unroll")                                                       \
  for (int i = 0; i < 4; ++i) { int idx = t + 256 * i;                    \
    Bs[bb][idx >> 6][idx & 63] = rb[i]; }
  TAIL_LOAD_A(kbeg)
  TAIL_LOAD_B(kbeg)
  TAIL_STORE(0)
  __syncthreads();
  int buf = 0;
  for (int k0 = kbeg; k0 < kbeg + kchunk; k0 += 16) {
    const bool more = (k0 + 16 < kbeg + kchunk);
    if (more) { TAIL_LOAD_A(k0 + 16) TAIL_LOAD_B(k0 + 16) }
    #pragma unroll
    for (int k = 0; k < 16; ++k) {
      float a[4], b[4];
      #pragma unroll
      for (int i = 0; i < 4; ++i) a[i] = As[buf][k][ty * 4 + i];
      #pragma unroll
      for (int j = 0; j < 4; ++j) b[j] = Bs[buf][k][tx * 4 + j];
      #pragma unroll
      for (int i = 0; i < 4; ++i)
        #pragma unroll
        for (int j = 0; j < 4; ++j) acc[i][j] += a[i] * b[j];
    }
    if (more) { TAIL_STORE(buf ^ 1) __syncthreads(); buf ^= 1; }
  }
  float* Cp = C + (size_t)blockIdx.z * (GNAMES * F2);
  #pragma unroll
  for (int i = 0; i < 4; ++i) {
    float4 v = make_float4(acc[i][0], acc[i][1], acc[i][2], acc[i][3]);
    *(float4*)&Cp[(size_t)(m0 + ty * 4 + i) * N + n0 + tx * 4] = v;
  }
}

// ---- sum S partial buffers, optional tanh ----
template<int ACT, int S>
__global__ __launch_bounds__(256) void k_reduce(const float* __restrict__ P,
                                                float* __restrict__ O,
                                                int len4, int stride4) {
  const int i = blockIdx.x * 256 + threadIdx.x;
  if (i >= len4) return;
  const float4* P4 = (const float4*)P;
  float4 a = P4[i];
  #pragma unroll
  for (int s = 1; s < S; ++s) {
    float4 b = P4[(size_t)s * stride4 + i];
    a.x += b.x; a.y += b.y; a.z += b.z; a.w += b.w;
  }
  if (ACT) { a.x = tanhf(a.x); a.y = tanhf(a.y); a.z = tanhf(a.z); a.w = tanhf(a.w); }
  ((float4*)O)[i] = a;
}

// ---- fused: in-block offsets + attention-mass histogram -> Wn[g][h][c] ----
// R10/R13 proven core (fp32, 4KB LDS): block = name, 256 thr = 4 waves,
// wave = word. Two-pass softmax via gathers (pass-2 re-gathers are L1-hot;
// R15 measured that caching them in LDS is NOT a win). LDS atomics to bins.
__global__ __launch_bounds__(256) void k_bins(const int* __restrict__ inputs,
                                              const int* __restrict__ nwords,
                                              const float* __restrict__ etab,
                                              float* __restrict__ Wn) {
  const int g = blockIdx.x, t = threadIdx.x;
  const int wv = t >> 6, l = t & 63;
  const int h = l & 7, qg = l >> 3;
  __shared__ float bins[VOC * NH];  // [c][h], 4 KB
  __shared__ int wred[4];
  __shared__ int sh_nwg;

  for (int i = t; i < VOC * NH; i += 256) bins[i] = 0.f;
  // in-block exclusive prefix: o0 = sum_{i<g} n_words[i], nw = n_words[g]
  int partial = 0;
  for (int i = t; i < GNAMES; i += 256) {
    int v = nwords[i];
    partial += (i < g) ? v : 0;
    if (i == g) sh_nwg = v;  // unique writer
  }
  #pragma unroll
  for (int d = 1; d < 64; d <<= 1) partial += __shfl_xor(partial, d);
  if (l == 0) wred[wv] = partial;
  __syncthreads();
  const int nw = sh_nwg;
  const int o0 = wred[0] + wred[1] + wred[2] + wred[3];

  for (int wrel = wv; wrel < nw; wrel += 4) {
    const int wi = o0 + wrel;
    int c_l = (l < LW) ? inputs[(size_t)wi * LW + l] : 0;
    unsigned long long mk = __ballot(c_l != 0);
    int cnt = __popcll(mk);
    float invc = cnt ? 1.f / (float)cnt : 0.f;

    int cq0 = __shfl(c_l, qg);
    int cq1 = __shfl(c_l, qg + 8);
    int cq2 = __shfl(c_l, qg + 16);
    const float* b0 = etab + (cq0 << 10) + h;
    const float* b1 = etab + (cq1 << 10) + h;
    const float* b2 = etab + (cq2 << 10) + h;

    // pass 1: gather rows, accumulate denominators
    float r0[LW], r1[LW], r2[LW];
    float d0 = 0.f, d1 = 0.f, d2 = 0.f;
    #pragma unroll
    for (int kp = 0; kp < LW; ++kp) {
      int o = __shfl(c_l, kp) << 3;
      r0[kp] = b0[o]; r1[kp] = b1[o]; r2[kp] = b2[o];
      d0 += r0[kp]; d1 += r1[kp]; d2 += r2[kp];
    }
    float i0 = cq0 ? invc / d0 : 0.f;
    float i1 = cq1 ? invc / d1 : 0.f;
    float i2 = cq2 ? invc / d2 : 0.f;

    // pass 2: weighting, q-reduce, scatter to char bins
    #pragma unroll
    for (int kp = 0; kp < LW; ++kp) {
      int ck = __shfl(c_l, kp);   // wave-uniform
      if (ck) {
        float v = r0[kp] * i0 + r1[kp] * i1 + r2[kp] * i2;
        v += __shfl_xor(v, 8);
        v += __shfl_xor(v, 16);
        v += __shfl_xor(v, 32);
        if (qg == 0) atomicAdd(&bins[(ck << 3) + h], v);
      }
    }
  }
  __syncthreads();

  // write Wn[g][h][c] from bins[c][h]
  const float invn = nw ? 1.f / (float)nw : 0.f;
  for (int i = t; i < NH * VOC; i += 256) {
    int hh = i >> 7, cc = i & 127;
    Wn[(size_t)g * 1024 + i] = bins[(cc << 3) + hh] * invn;
  }
}

extern "C" void kernel_launch(void* const* d_in, const int* in_sizes, int n_in,
                              void* d_out, int out_size, void* d_ws, size_t ws_size,
                              hipStream_t stream) {
  const int*   inputs  = (const int*)d_in[0];
  const int*   n_words = (const int*)d_in[1];
  const float* emb     = (const float*)d_in[3];
  const float* Wq      = (const float*)d_in[4];
  const float* Wk      = (const float*)d_in[5];
  const float* Wv      = (const float*)d_in[6];
  const float* Wo      = (const float*)d_in[7];
  const float* W1      = (const float*)d_in[8];
  const float* W2      = (const float*)d_in[9];
  float* out = (float*)d_out;

  // workspace layout (floats), ~60 MB (d_ws is 256 MB per poison-fill size)
  float* ws   = (float*)d_ws;
  float* BIG  = ws;                     // 4 x S1_LEN = 1,835,008: raw stage-1 partials
  float* TAB  = ws + 1835008;           // 131,072: exp table [c1][c2][h]
  float* EVW  = ws + 1966080;           // 1024*512 = 524,288
  float* Wn   = ws + 2490368;           // 2048*1024 = 2,097,152
  float* ILVP = ws + 4587520;           // 8 x 2048*512 = 8,388,608 (interleaved)
  float* OUTP = ws + 12976128;          // 4 x 2048*256 = 2,097,152

  // 1) stage-1 fused GEMMs, split-K=4 -> 448 blocks, raw partials only
  k_stage1<4><<<dim3(112, 4), 256, 0, stream>>>(emb, Wq, Wk, Wv, Wo, W1, BIG);
  // 2) exp-table tiles + EVW tiles, folding the 4-partial sums (reduce dead)
  k_tab_evw<<<160, 256, 0, stream>>>(BIG, TAB, EVW);
  // 3) fused offsets + histogram -> Wn
  k_bins<<<GNAMES, 256, 0, stream>>>(inputs, n_words, TAB, Wn);
  // 4) G = Wn @ EVW (K=1024), split-K=8 -> 2048 blocks, interleaved partials
  k_gemm_ilv<<<dim3(8, 32, 8), 256, 0, stream>>>(Wn, EVW, ILVP, 128);
  // 5) out_partials = tanh(sum 8 partials) @ W2, split-K=4
  k_gemm_tail<<<dim3(4, 32, 4), 256, 0, stream>>>(ILVP, W2, OUTP, 128);
  // 6) out = tanh(sum out_partials)
  k_reduce<1, 4><<<(GNAMES * F2) / 4 / 256, 256, 0, stream>>>(OUTP, out, (GNAMES * F2) / 4, (GNAMES * F2) / 4);
}

// Round 18
// 105.711 us; speedup vs baseline: 1.2323x; 1.2323x over previous
//
#include <hip/hip_runtime.h>
#include <math.h>

// Problem constants (fixed by setup_inputs)
#define NWORDS 8192
#define LW     24
#define VOC    128
#define DIM    512
#define NH     8
#define DKH    64
#define GNAMES 2048
#define F2     256

// stage-1 fused output layout (floats): [EQ 65536 | EK 65536 | EV 65536 | WF 262144]
#define S1_LEN 458752

// =================== double-buffered 64x64 fp32 GEMM body ====================
// 256 threads, BK=16, 4x4 register tile, one barrier per K-step.
// K_ is used as lda, N_ as ldb only.
#define GEMM_BODY(A_, B_, K_, N_, m0_, n0_, kbeg_, kchunk_)                         \
  __shared__ float As[2][16][68];                                                   \
  __shared__ float Bs[2][16][68];                                                   \
  const int t = threadIdx.x, tx = t & 15, ty = t >> 4;                              \
  float acc[4][4] = {};                                                             \
  float ra[4], rb[4];                                                               \
  _Pragma("unroll")                                                                 \
  for (int i = 0; i < 4; ++i) { int idx = t + 256 * i;                              \
    ra[i] = A_[(size_t)(m0_ + (idx >> 4)) * K_ + kbeg_ + (idx & 15)]; }             \
  _Pragma("unroll")                                                                 \
  for (int i = 0; i < 4; ++i) { int idx = t + 256 * i;                              \
    rb[i] = B_[(size_t)(kbeg_ + (idx >> 6)) * N_ + n0_ + (idx & 63)]; }             \
  _Pragma("unroll")                                                                 \
  for (int i = 0; i < 4; ++i) { int idx = t + 256 * i; As[0][idx & 15][idx >> 4] = ra[i]; } \
  _Pragma("unroll")                                                                 \
  for (int i = 0; i < 4; ++i) { int idx = t + 256 * i; Bs[0][idx >> 6][idx & 63] = rb[i]; } \
  __syncthreads();                                                                  \
  int buf = 0;                                                                      \
  for (int k0 = kbeg_; k0 < kbeg_ + kchunk_; k0 += 16) {                            \
    const bool more = (k0 + 16 < kbeg_ + kchunk_);                                  \
    if (more) {                                                                     \
      _Pragma("unroll")                                                             \
      for (int i = 0; i < 4; ++i) { int idx = t + 256 * i;                          \
        ra[i] = A_[(size_t)(m0_ + (idx >> 4)) * K_ + (k0 + 16) + (idx & 15)]; }     \
      _Pragma("unroll")                                                             \
      for (int i = 0; i < 4; ++i) { int idx = t + 256 * i;                          \
        rb[i] = B_[(size_t)(k0 + 16 + (idx >> 6)) * N_ + n0_ + (idx & 63)]; }       \
    }                                                                               \
    _Pragma("unroll")                                                               \
    for (int k = 0; k < 16; ++k) {                                                  \
      float a[4], b[4];                                                             \
      _Pragma("unroll")                                                             \
      for (int i = 0; i < 4; ++i) a[i] = As[buf][k][ty * 4 + i];                    \
      _Pragma("unroll")                                                             \
      for (int j = 0; j < 4; ++j) b[j] = Bs[buf][k][tx * 4 + j];                    \
      _Pragma("unroll")                                                             \
      for (int i = 0; i < 4; ++i)                                                   \
        _Pragma("unroll")                                                           \
        for (int j = 0; j < 4; ++j) acc[i][j] += a[i] * b[j];                       \
    }                                                                               \
    if (more) {                                                                     \
      _Pragma("unroll")                                                             \
      for (int i = 0; i < 4; ++i) { int idx = t + 256 * i; As[buf ^ 1][idx & 15][idx >> 4] = ra[i]; } \
      _Pragma("unroll")                                                             \
      for (int i = 0; i < 4; ++i) { int idx = t + 256 * i; Bs[buf ^ 1][idx >> 6][idx & 63] = rb[i]; } \
      __syncthreads();                                                              \
      buf ^= 1;                                                                     \
    }                                                                               \
  }

// ---- stage-1 fused GEMM: EQ/EK/EV (128x512) + WF=Wo@W1 (512x512), all K=512 ----
template<int NSPLIT>
__global__ __launch_bounds__(256) void k_stage1(const float* __restrict__ emb,
                                                const float* __restrict__ Wq,
                                                const float* __restrict__ Wk,
                                                const float* __restrict__ Wv,
                                                const float* __restrict__ Wo,
                                                const float* __restrict__ W1,
                                                float* __restrict__ P) {
  const int tid = blockIdx.x, s = blockIdx.y;
  const float *A, *B;
  int coff, m0, n0;
  if (tid < 48) {
    const int g = tid >> 4, mt = tid & 15;
    A = emb;
    B = (g == 0) ? Wq : ((g == 1) ? Wk : Wv);
    coff = g * 65536;
    m0 = (mt >> 3) * 64; n0 = (mt & 7) * 64;
  } else {
    const int id = tid - 48;
    A = Wo; B = W1; coff = 3 * 65536;
    m0 = (id >> 3) * 64; n0 = (id & 7) * 64;
  }
  const int kchunk = 512 / NSPLIT, kbeg = s * kchunk;
  GEMM_BODY(A, B, 512, 512, m0, n0, kbeg, kchunk)
  float* Cp = P + (size_t)s * S1_LEN + coff;
  #pragma unroll
  for (int i = 0; i < 4; ++i) {
    float4 v = make_float4(acc[i][0], acc[i][1], acc[i][2], acc[i][3]);
    *(float4*)&Cp[(size_t)(m0 + ty * 4 + i) * 512 + n0 + tx * 4] = v;
  }
}

// ---- NP @ WF with INTERLEAVED split-K partial store ----
// P layout (floats): [m][k4][s][4] -> float4 index (m*128 + k4)*4 + s.
__global__ __launch_bounds__(256) void k_gemm_ilv(const float* __restrict__ A,
                                                  const float* __restrict__ B,
                                                  float* __restrict__ P,
                                                  int kchunk) {
  const int m0 = blockIdx.y * 64, n0 = blockIdx.x * 64;
  const int kbeg = blockIdx.z * kchunk;
  const int sz = blockIdx.z;
  GEMM_BODY(A, B, 512, 512, m0, n0, kbeg, kchunk)
  float4* P4 = (float4*)P;
  #pragma unroll
  for (int i = 0; i < 4; ++i) {
    float4 v = make_float4(acc[i][0], acc[i][1], acc[i][2], acc[i][3]);
    P4[((size_t)(m0 + ty * 4 + i) * 128 + (n0 >> 2) + tx) * 4 + sz] = v;
  }
}

// ---- name-pool GEMM: NP[m, h*64+n] = sum_c Wn[m][h*128+c] * EV[c][h*64+n] ----
__global__ __launch_bounds__(256) void k_npool(const float* __restrict__ Wn,
                                               const float* __restrict__ EV,
                                               float* __restrict__ NP) {
  const int m0 = blockIdx.x * 64, h = blockIdx.y;
  const float* A2 = Wn + (size_t)m0 * 1024 + h * 128;   // lda 1024
  const float* B2 = EV + h * 64;                        // ldb 512
  GEMM_BODY(A2, B2, 1024, 512, 0, 0, 0, 128)
  #pragma unroll
  for (int i = 0; i < 4; ++i) {
    float4 v = make_float4(acc[i][0], acc[i][1], acc[i][2], acc[i][3]);
    *(float4*)&NP[(size_t)(m0 + ty * 4 + i) * 512 + h * 64 + tx * 4] = v;
  }
}

// ---- tail GEMM: A = tanh(sum of 4 interleaved partials), B = W2 ----
// A-fill per thread: one (m, k4-group) -> 4 contiguous float4 loads (64B),
// component-wise sum, 4 tanh, 4 LDS stores. split over gridDim.z.
__global__ __launch_bounds__(256) void k_gemm_tail(const float* __restrict__ P,
                                                   const float* __restrict__ B,
                                                   float* __restrict__ C,
                                                   int kchunk) {
  const int N = 256, K = 512;
  __shared__ float As[2][16][68];
  __shared__ float Bs[2][16][68];
  const int t = threadIdx.x, tx = t & 15, ty = t >> 4;
  const int m0 = blockIdx.y * 64, n0 = blockIdx.x * 64;
  const int kbeg = blockIdx.z * kchunk;
  const float4* P4 = (const float4*)P;
  const int am = t >> 2, ak = t & 3;   // A map: 64 rows x 4 k4-groups
  float acc[4][4] = {};
  float4 ta;
  float rb[4];
#define TAIL_LOAD_A(kb)                                                   \
  {                                                                       \
    size_t b4 = ((size_t)(m0 + am) * 128 + ((kb) >> 2) + ak) * 4;         \
    float4 p0 = P4[b4 + 0], p1 = P4[b4 + 1], p2 = P4[b4 + 2], p3 = P4[b4 + 3]; \
    ta.x = tanhf(p0.x + p1.x + p2.x + p3.x);                              \
    ta.y = tanhf(p0.y + p1.y + p2.y + p3.y);                              \
    ta.z = tanhf(p0.z + p1.z + p2.z + p3.z);                              \
    ta.w = tanhf(p0.w + p1.w + p2.w + p3.w);                              \
  }
#define TAIL_LOAD_B(kb)                                                   \
  _Pragma("unroll")                                                       \
  for (int i = 0; i < 4; ++i) { int idx = t + 256 * i;                    \
    rb[i] = B[(size_t)((kb) + (idx >> 6)) * N + n0 + (idx & 63)]; }
#define TAIL_STORE(bb)                                                    \
  { int kk = ak * 4;                                                      \
    As[bb][kk + 0][am] = ta.x; As[bb][kk + 1][am] = ta.y;                 \
    As[bb][kk + 2][am] = ta.z; As[bb][kk + 3][am] = ta.w; }               \
  _Pragma("unroll")                                                       \
  for (int i = 0; i < 4; ++i) { int idx = t + 256 * i;                    \
    Bs[bb][idx >> 6][idx & 63] = rb[i]; }
  TAIL_LOAD_A(kbeg)
  TAIL_LOAD_B(kbeg)
  TAIL_STORE(0)
  __syncthreads();
  int buf = 0;
  for (int k0 = kbeg; k0 < kbeg + kchunk; k0 += 16) {
    const bool more = (k0 + 16 < kbeg + kchunk);
    if (more) { TAIL_LOAD_A(k0 + 16) TAIL_LOAD_B(k0 + 16) }
    #pragma unroll
    for (int k = 0; k < 16; ++k) {
      float a[4], b[4];
      #pragma unroll
      for (int i = 0; i < 4; ++i) a[i] = As[buf][k][ty * 4 + i];
      #pragma unroll
      for (int j = 0; j < 4; ++j) b[j] = Bs[buf][k][tx * 4 + j];
      #pragma unroll
      for (int i = 0; i < 4; ++i)
        #pragma unroll
        for (int j = 0; j < 4; ++j) acc[i][j] += a[i] * b[j];
    }
    if (more) { TAIL_STORE(buf ^ 1) __syncthreads(); buf ^= 1; }
  }
  float* Cp = C + (size_t)blockIdx.z * (GNAMES * F2);
  #pragma unroll
  for (int i = 0; i < 4; ++i) {
    float4 v = make_float4(acc[i][0], acc[i][1], acc[i][2], acc[i][3]);
    *(float4*)&Cp[(size_t)(m0 + ty * 4 + i) * N + n0 + tx * 4] = v;
  }
}

// ---- sum S partial buffers, optional tanh ----
template<int ACT, int S>
__global__ __launch_bounds__(256) void k_reduce(const float* __restrict__ P,
                                                float* __restrict__ O,
                                                int len4, int stride4) {
  const int i = blockIdx.x * 256 + threadIdx.x;
  if (i >= len4) return;
  const float4* P4 = (const float4*)P;
  float4 a = P4[i];
  #pragma unroll
  for (int s = 1; s < S; ++s) {
    float4 b = P4[(size_t)s * stride4 + i];
    a.x += b.x; a.y += b.y; a.z += b.z; a.w += b.w;
  }
  if (ACT) { a.x = tanhf(a.x); a.y = tanhf(a.y); a.z = tanhf(a.z); a.w = tanhf(a.w); }
  ((float4*)O)[i] = a;
}

// ---- exp(qk) table, zeroed on pad rows/cols: ETAB[c1][c2][h] ----
__global__ __launch_bounds__(128) void k_qk_tab(const float* __restrict__ EQ,
                                                const float* __restrict__ EK,
                                                float* __restrict__ etab) {
  const int c1 = blockIdx.x, h = blockIdx.y, c2 = threadIdx.x;
  __shared__ float qrow[DKH];
  if (threadIdx.x < DKH) qrow[threadIdx.x] = EQ[c1 * DIM + h * DKH + threadIdx.x];
  __syncthreads();
  const float* krow = EK + c2 * DIM + h * DKH;
  float acc = 0.f;
  #pragma unroll
  for (int d = 0; d < DKH; ++d) acc += qrow[d] * krow[d];
  float e = (c1 != 0 && c2 != 0) ? __expf(acc * 0.125f) : 0.f;
  etab[((size_t)c1 * VOC + c2) * NH + h] = e;
}

// ---- fused: in-block offsets + attention-mass histogram -> Wn[g][h][c] ----
// R10/R13 proven core (fp32, 4KB LDS): block = name, 256 thr = 4 waves,
// wave = word. Two-pass softmax via gathers (pass-2 re-gathers are L1-hot;
// R15 measured that caching them in LDS is NOT a win). LDS atomics to bins.
__global__ __launch_bounds__(256) void k_bins(const int* __restrict__ inputs,
                                              const int* __restrict__ nwords,
                                              const float* __restrict__ etab,
                                              float* __restrict__ Wn) {
  const int g = blockIdx.x, t = threadIdx.x;
  const int wv = t >> 6, l = t & 63;
  const int h = l & 7, qg = l >> 3;
  __shared__ float bins[VOC * NH];  // [c][h], 4 KB
  __shared__ int wred[4];
  __shared__ int sh_nwg;

  for (int i = t; i < VOC * NH; i += 256) bins[i] = 0.f;
  // in-block exclusive prefix: o0 = sum_{i<g} n_words[i], nw = n_words[g]
  int partial = 0;
  for (int i = t; i < GNAMES; i += 256) {
    int v = nwords[i];
    partial += (i < g) ? v : 0;
    if (i == g) sh_nwg = v;  // unique writer
  }
  #pragma unroll
  for (int d = 1; d < 64; d <<= 1) partial += __shfl_xor(partial, d);
  if (l == 0) wred[wv] = partial;
  __syncthreads();
  const int nw = sh_nwg;
  const int o0 = wred[0] + wred[1] + wred[2] + wred[3];

  for (int wrel = wv; wrel < nw; wrel += 4) {
    const int wi = o0 + wrel;
    int c_l = (l < LW) ? inputs[(size_t)wi * LW + l] : 0;
    unsigned long long mk = __ballot(c_l != 0);
    int cnt = __popcll(mk);
    float invc = cnt ? 1.f / (float)cnt : 0.f;

    int cq0 = __shfl(c_l, qg);
    int cq1 = __shfl(c_l, qg + 8);
    int cq2 = __shfl(c_l, qg + 16);
    const float* b0 = etab + (cq0 << 10) + h;
    const float* b1 = etab + (cq1 << 10) + h;
    const float* b2 = etab + (cq2 << 10) + h;

    // pass 1: gather rows, accumulate denominators
    float r0[LW], r1[LW], r2[LW];
    float d0 = 0.f, d1 = 0.f, d2 = 0.f;
    #pragma unroll
    for (int kp = 0; kp < LW; ++kp) {
      int o = __shfl(c_l, kp) << 3;
      r0[kp] = b0[o]; r1[kp] = b1[o]; r2[kp] = b2[o];
      d0 += r0[kp]; d1 += r1[kp]; d2 += r2[kp];
    }
    float i0 = cq0 ? invc / d0 : 0.f;
    float i1 = cq1 ? invc / d1 : 0.f;
    float i2 = cq2 ? invc / d2 : 0.f;

    // pass 2: weighting, q-reduce, scatter to char bins
    #pragma unroll
    for (int kp = 0; kp < LW; ++kp) {
      int ck = __shfl(c_l, kp);   // wave-uniform
      if (ck) {
        float v = r0[kp] * i0 + r1[kp] * i1 + r2[kp] * i2;
        v += __shfl_xor(v, 8);
        v += __shfl_xor(v, 16);
        v += __shfl_xor(v, 32);
        if (qg == 0) atomicAdd(&bins[(ck << 3) + h], v);
      }
    }
  }
  __syncthreads();

  // write Wn[g][h][c] from bins[c][h]
  const float invn = nw ? 1.f / (float)nw : 0.f;
  for (int i = t; i < NH * VOC; i += 256) {
    int hh = i >> 7, cc = i & 127;
    Wn[(size_t)g * 1024 + i] = bins[(cc << 3) + hh] * invn;
  }
}

extern "C" void kernel_launch(void* const* d_in, const int* in_sizes, int n_in,
                              void* d_out, int out_size, void* d_ws, size_t ws_size,
                              hipStream_t stream) {
  const int*   inputs  = (const int*)d_in[0];
  const int*   n_words = (const int*)d_in[1];
  const float* emb     = (const float*)d_in[3];
  const float* Wq      = (const float*)d_in[4];
  const float* Wk      = (const float*)d_in[5];
  const float* Wv      = (const float*)d_in[6];
  const float* Wo      = (const float*)d_in[7];
  const float* W1      = (const float*)d_in[8];
  const float* W2      = (const float*)d_in[9];
  float* out = (float*)d_out;

  // workspace layout (floats), ~40 MB (d_ws is 256 MB per poison-fill size)
  float* ws   = (float*)d_ws;
  float* ES   = ws;                     // 458752: [EQ|EK|EV|WF]
  float* BIG  = ws + 458752;            // 4194304: stage1 partials (planar) / NP@WF partials (interleaved)
  float* TAB  = ws + 4653056;           // 131072: exp table [c1][c2][h]
  float* NP   = ws + 4784128;           // 2048*512
  float* Wn   = ws + 5832704;           // 2048*1024 = 2097152
  float* OUTP = ws + 7929856;           // 4 x 2048*256 out partials

  // stage-1 fused GEMMs, split-K=4 -> 448 blocks
  k_stage1<4><<<dim3(112, 4), 256, 0, stream>>>(emb, Wq, Wk, Wv, Wo, W1, BIG);
  k_reduce<0, 4><<<S1_LEN / 4 / 256, 256, 0, stream>>>(BIG, ES, S1_LEN / 4, S1_LEN / 4);
  // exp(qk) table from EQ, EK (pad rows/cols zeroed)
  k_qk_tab<<<dim3(VOC, NH), 128, 0, stream>>>(ES, ES + 65536, TAB);
  // fused offsets + histogram -> Wn
  k_bins<<<GNAMES, 256, 0, stream>>>(inputs, n_words, TAB, Wn);
  // NP = per-head Wn @ EV (tiled GEMM, EV reuse through LDS)
  k_npool<<<dim3(GNAMES / 64, NH), 256, 0, stream>>>(Wn, ES + 131072, NP);
  // NP @ WF, split-K=4 -> INTERLEAVED partials in BIG (stage1 partials dead)
  k_gemm_ilv<<<dim3(8, 32, 4), 256, 0, stream>>>(NP, ES + 196608, BIG, 128);
  // out_partials = tanh(sum interleaved partials) @ W2, split-K=4
  k_gemm_tail<<<dim3(4, 32, 4), 256, 0, stream>>>(BIG, W2, OUTP, 128);
  // out = tanh(sum out_partials)
  k_reduce<1, 4><<<(GNAMES * F2) / 4 / 256, 256, 0, stream>>>(OUTP, out, (GNAMES * F2) / 4, (GNAMES * F2) / 4);
}

// Round 19
// 105.472 us; speedup vs baseline: 1.2351x; 1.0023x over previous
//
#include <hip/hip_runtime.h>
#include <math.h>

// Problem constants (fixed by setup_inputs)
#define NWORDS 8192
#define LW     24
#define VOC    128
#define DIM    512
#define NH     8
#define DKH    64
#define GNAMES 2048
#define F2     256

// stage-1 fused output layout (floats): [EQ 65536 | EK 65536 | EV 65536 | WF 262144]
#define S1_LEN 458752

// =================== double-buffered 64x64 fp32 GEMM body ====================
// 256 threads, BK=16, 4x4 register tile, one barrier per K-step.
// K_ is used as lda, N_ as ldb only.
#define GEMM_BODY(A_, B_, K_, N_, m0_, n0_, kbeg_, kchunk_)                         \
  __shared__ float As[2][16][68];                                                   \
  __shared__ float Bs[2][16][68];                                                   \
  const int t = threadIdx.x, tx = t & 15, ty = t >> 4;                              \
  float acc[4][4] = {};                                                             \
  float ra[4], rb[4];                                                               \
  _Pragma("unroll")                                                                 \
  for (int i = 0; i < 4; ++i) { int idx = t + 256 * i;                              \
    ra[i] = A_[(size_t)(m0_ + (idx >> 4)) * K_ + kbeg_ + (idx & 15)]; }             \
  _Pragma("unroll")                                                                 \
  for (int i = 0; i < 4; ++i) { int idx = t + 256 * i;                              \
    rb[i] = B_[(size_t)(kbeg_ + (idx >> 6)) * N_ + n0_ + (idx & 63)]; }             \
  _Pragma("unroll")                                                                 \
  for (int i = 0; i < 4; ++i) { int idx = t + 256 * i; As[0][idx & 15][idx >> 4] = ra[i]; } \
  _Pragma("unroll")                                                                 \
  for (int i = 0; i < 4; ++i) { int idx = t + 256 * i; Bs[0][idx >> 6][idx & 63] = rb[i]; } \
  __syncthreads();                                                                  \
  int buf = 0;                                                                      \
  for (int k0 = kbeg_; k0 < kbeg_ + kchunk_; k0 += 16) {                            \
    const bool more = (k0 + 16 < kbeg_ + kchunk_);                                  \
    if (more) {                                                                     \
      _Pragma("unroll")                                                             \
      for (int i = 0; i < 4; ++i) { int idx = t + 256 * i;                          \
        ra[i] = A_[(size_t)(m0_ + (idx >> 4)) * K_ + (k0 + 16) + (idx & 15)]; }     \
      _Pragma("unroll")                                                             \
      for (int i = 0; i < 4; ++i) { int idx = t + 256 * i;                          \
        rb[i] = B_[(size_t)(k0 + 16 + (idx >> 6)) * N_ + n0_ + (idx & 63)]; }       \
    }                                                                               \
    _Pragma("unroll")                                                               \
    for (int k = 0; k < 16; ++k) {                                                  \
      float a[4], b[4];                                                             \
      _Pragma("unroll")                                                             \
      for (int i = 0; i < 4; ++i) a[i] = As[buf][k][ty * 4 + i];                    \
      _Pragma("unroll")                                                             \
      for (int j = 0; j < 4; ++j) b[j] = Bs[buf][k][tx * 4 + j];                    \
      _Pragma("unroll")                                                             \
      for (int i = 0; i < 4; ++i)                                                   \
        _Pragma("unroll")                                                           \
        for (int j = 0; j < 4; ++j) acc[i][j] += a[i] * b[j];                       \
    }                                                                               \
    if (more) {                                                                     \
      _Pragma("unroll")                                                             \
      for (int i = 0; i < 4; ++i) { int idx = t + 256 * i; As[buf ^ 1][idx & 15][idx >> 4] = ra[i]; } \
      _Pragma("unroll")                                                             \
      for (int i = 0; i < 4; ++i) { int idx = t + 256 * i; Bs[buf ^ 1][idx >> 6][idx & 63] = rb[i]; } \
      __syncthreads();                                                              \
      buf ^= 1;                                                                     \
    }                                                                               \
  }

// ---- stage-1 fused GEMM: EQ/EK/EV (128x512) + WF=Wo@W1 (512x512), all K=512 ----
// split-K=4, raw planar partials P[s][S1_LEN]; consumers fold the 4-way sum.
template<int NSPLIT>
__global__ __launch_bounds__(256) void k_stage1(const float* __restrict__ emb,
                                                const float* __restrict__ Wq,
                                                const float* __restrict__ Wk,
                                                const float* __restrict__ Wv,
                                                const float* __restrict__ Wo,
                                                const float* __restrict__ W1,
                                                float* __restrict__ P) {
  const int tid = blockIdx.x, s = blockIdx.y;
  const float *A, *B;
  int coff, m0, n0;
  if (tid < 48) {
    const int g = tid >> 4, mt = tid & 15;
    A = emb;
    B = (g == 0) ? Wq : ((g == 1) ? Wk : Wv);
    coff = g * 65536;
    m0 = (mt >> 3) * 64; n0 = (mt & 7) * 64;
  } else {
    const int id = tid - 48;
    A = Wo; B = W1; coff = 3 * 65536;
    m0 = (id >> 3) * 64; n0 = (id & 7) * 64;
  }
  const int kchunk = 512 / NSPLIT, kbeg = s * kchunk;
  GEMM_BODY(A, B, 512, 512, m0, n0, kbeg, kchunk)
  float* Cp = P + (size_t)s * S1_LEN + coff;
  #pragma unroll
  for (int i = 0; i < 4; ++i) {
    float4 v = make_float4(acc[i][0], acc[i][1], acc[i][2], acc[i][3]);
    *(float4*)&Cp[(size_t)(m0 + ty * 4 + i) * 512 + n0 + tx * 4] = v;
  }
}

// ---- fused: exp-table tiles (fold 4-partial sums inline, R17-proven) +
// elementwise reduce of the EV/WF region into EVWF (npool/ilv consume it).
//   blocks [0,32):   tab tile. h=b>>2, mt=(b>>1)&1, nt=b&1. 64x64 of
//                    etab[c1][c2][h] = exp(0.125*dot(EQ_h[c1],EK_h[c2])),
//                    zeroed on pad rows/cols.
//   blocks [32,352): reduce. float4 idx4 = (b-32)*256 + t over EV|WF
//                    (327680 floats), EVWF[idx] = sum of 4 planes.
__global__ __launch_bounds__(256) void k_qk_tab2(const float* __restrict__ P,
                                                 float* __restrict__ etab,
                                                 float* __restrict__ EVWF) {
  const int b = blockIdx.x, t = threadIdx.x;
  if (b >= 32) {
    const int idx4 = (b - 32) * 256 + t;   // < 81920
    const float4* P4 = (const float4*)(P + 131072);
    const int S4 = S1_LEN / 4;
    float4 a = P4[idx4];
    float4 p1 = P4[idx4 + S4], p2 = P4[idx4 + 2 * S4], p3 = P4[idx4 + 3 * S4];
    a.x += p1.x + p2.x + p3.x;
    a.y += p1.y + p2.y + p3.y;
    a.z += p1.z + p2.z + p3.z;
    a.w += p1.w + p2.w + p3.w;
    ((float4*)EVWF)[idx4] = a;
    return;
  }
  __shared__ float As[64][65];
  __shared__ float Bs[64][65];
  const int tx = t & 15, ty = t >> 4;
  const int h = b >> 2, mt = (b >> 1) & 1, nt = b & 1;
  const int m0 = mt * 64, n0 = nt * 64;
  #pragma unroll
  for (int i = 0; i < 16; ++i) {
    int idx = t + 256 * i;          // 0..4095
    int r = idx >> 6, d = idx & 63;
    size_t ao = (size_t)(m0 + r) * 512 + h * 64 + d;            // EQ row r
    As[d][r] = P[ao] + P[ao + S1_LEN] + P[ao + 2 * S1_LEN] + P[ao + 3 * S1_LEN];
    size_t bo = 65536 + (size_t)(n0 + r) * 512 + h * 64 + d;    // EK row r
    Bs[d][r] = P[bo] + P[bo + S1_LEN] + P[bo + 2 * S1_LEN] + P[bo + 3 * S1_LEN];
  }
  __syncthreads();
  float acc[4][4] = {};
  for (int d = 0; d < 64; ++d) {
    float a[4], bb[4];
    #pragma unroll
    for (int i = 0; i < 4; ++i) a[i] = As[d][ty * 4 + i];
    #pragma unroll
    for (int j = 0; j < 4; ++j) bb[j] = Bs[d][tx * 4 + j];
    #pragma unroll
    for (int i = 0; i < 4; ++i)
      #pragma unroll
      for (int j = 0; j < 4; ++j) acc[i][j] += a[i] * bb[j];
  }
  #pragma unroll
  for (int i = 0; i < 4; ++i) {
    int c1 = m0 + ty * 4 + i;
    #pragma unroll
    for (int j = 0; j < 4; ++j) {
      int c2 = n0 + tx * 4 + j;
      float e = (c1 != 0 && c2 != 0) ? __expf(acc[i][j] * 0.125f) : 0.f;
      etab[((size_t)c1 * VOC + c2) * NH + h] = e;
    }
  }
}

// ---- NP @ WF with INTERLEAVED split-K partial store ----
// P layout (floats): [m][k4][s][4] -> float4 index (m*128 + k4)*4 + s.
__global__ __launch_bounds__(256) void k_gemm_ilv(const float* __restrict__ A,
                                                  const float* __restrict__ B,
                                                  float* __restrict__ P,
                                                  int kchunk) {
  const int m0 = blockIdx.y * 64, n0 = blockIdx.x * 64;
  const int kbeg = blockIdx.z * kchunk;
  const int sz = blockIdx.z;
  GEMM_BODY(A, B, 512, 512, m0, n0, kbeg, kchunk)
  float4* P4 = (float4*)P;
  #pragma unroll
  for (int i = 0; i < 4; ++i) {
    float4 v = make_float4(acc[i][0], acc[i][1], acc[i][2], acc[i][3]);
    P4[((size_t)(m0 + ty * 4 + i) * 128 + (n0 >> 2) + tx) * 4 + sz] = v;
  }
}

// ---- name-pool GEMM: NP[m, h*64+n] = sum_c Wn[m][h*128+c] * EV[c][h*64+n] ----
__global__ __launch_bounds__(256) void k_npool(const float* __restrict__ Wn,
                                               const float* __restrict__ EV,
                                               float* __restrict__ NP) {
  const int m0 = blockIdx.x * 64, h = blockIdx.y;
  const float* A2 = Wn + (size_t)m0 * 1024 + h * 128;   // lda 1024
  const float* B2 = EV + h * 64;                        // ldb 512
  GEMM_BODY(A2, B2, 1024, 512, 0, 0, 0, 128)
  #pragma unroll
  for (int i = 0; i < 4; ++i) {
    float4 v = make_float4(acc[i][0], acc[i][1], acc[i][2], acc[i][3]);
    *(float4*)&NP[(size_t)(m0 + ty * 4 + i) * 512 + h * 64 + tx * 4] = v;
  }
}

// ---- tail GEMM: A = tanh(sum of 4 interleaved partials), B = W2 ----
__global__ __launch_bounds__(256) void k_gemm_tail(const float* __restrict__ P,
                                                   const float* __restrict__ B,
                                                   float* __restrict__ C,
                                                   int kchunk) {
  const int N = 256, K = 512;
  __shared__ float As[2][16][68];
  __shared__ float Bs[2][16][68];
  const int t = threadIdx.x, tx = t & 15, ty = t >> 4;
  const int m0 = blockIdx.y * 64, n0 = blockIdx.x * 64;
  const int kbeg = blockIdx.z * kchunk;
  const float4* P4 = (const float4*)P;
  const int am = t >> 2, ak = t & 3;   // A map: 64 rows x 4 k4-groups
  float acc[4][4] = {};
  float4 ta;
  float rb[4];
#define TAIL_LOAD_A(kb)                                                   \
  {                                                                       \
    size_t b4 = ((size_t)(m0 + am) * 128 + ((kb) >> 2) + ak) * 4;         \
    float4 p0 = P4[b4 + 0], p1 = P4[b4 + 1], p2 = P4[b4 + 2], p3 = P4[b4 + 3]; \
    ta.x = tanhf(p0.x + p1.x + p2.x + p3.x);                              \
    ta.y = tanhf(p0.y + p1.y + p2.y + p3.y);                              \
    ta.z = tanhf(p0.z + p1.z + p2.z + p3.z);                              \
    ta.w = tanhf(p0.w + p1.w + p2.w + p3.w);                              \
  }
#define TAIL_LOAD_B(kb)                                                   \
  _Pragma("unroll")                                                       \
  for (int i = 0; i < 4; ++i) { int idx = t + 256 * i;                    \
    rb[i] = B[(size_t)((kb) + (idx >> 6)) * N + n0 + (idx & 63)]; }
#define TAIL_STORE(bb)                                                    \
  { int kk = ak * 4;                                                      \
    As[bb][kk + 0][am] = ta.x; As[bb][kk + 1][am] = ta.y;                 \
    As[bb][kk + 2][am] = ta.z; As[bb][kk + 3][am] = ta.w; }               \
  _Pragma("unroll")                                                       \
  for (int i = 0; i < 4; ++i) { int idx = t + 256 * i;                    \
    Bs[bb][idx >> 6][idx & 63] = rb[i]; }
  TAIL_LOAD_A(kbeg)
  TAIL_LOAD_B(kbeg)
  TAIL_STORE(0)
  __syncthreads();
  int buf = 0;
  for (int k0 = kbeg; k0 < kbeg + kchunk; k0 += 16) {
    const bool more = (k0 + 16 < kbeg + kchunk);
    if (more) { TAIL_LOAD_A(k0 + 16) TAIL_LOAD_B(k0 + 16) }
    #pragma unroll
    for (int k = 0; k < 16; ++k) {
      float a[4], b[4];
      #pragma unroll
      for (int i = 0; i < 4; ++i) a[i] = As[buf][k][ty * 4 + i];
      #pragma unroll
      for (int j = 0; j < 4; ++j) b[j] = Bs[buf][k][tx * 4 + j];
      #pragma unroll
      for (int i = 0; i < 4; ++i)
        #pragma unroll
        for (int j = 0; j < 4; ++j) acc[i][j] += a[i] * b[j];
    }
    if (more) { TAIL_STORE(buf ^ 1) __syncthreads(); buf ^= 1; }
  }
  float* Cp = C + (size_t)blockIdx.z * (GNAMES * F2);
  #pragma unroll
  for (int i = 0; i < 4; ++i) {
    float4 v = make_float4(acc[i][0], acc[i][1], acc[i][2], acc[i][3]);
    *(float4*)&Cp[(size_t)(m0 + ty * 4 + i) * N + n0 + tx * 4] = v;
  }
}

// ---- sum S partial buffers, optional tanh ----
template<int ACT, int S>
__global__ __launch_bounds__(256) void k_reduce(const float* __restrict__ P,
                                                float* __restrict__ O,
                                                int len4, int stride4) {
  const int i = blockIdx.x * 256 + threadIdx.x;
  if (i >= len4) return;
  const float4* P4 = (const float4*)P;
  float4 a = P4[i];
  #pragma unroll
  for (int s = 1; s < S; ++s) {
    float4 b = P4[(size_t)s * stride4 + i];
    a.x += b.x; a.y += b.y; a.z += b.z; a.w += b.w;
  }
  if (ACT) { a.x = tanhf(a.x); a.y = tanhf(a.y); a.z = tanhf(a.z); a.w = tanhf(a.w); }
  ((float4*)O)[i] = a;
}

// ---- fused: in-block offsets + attention-mass histogram -> Wn[g][h][c] ----
// R10/R13 proven core (fp32, 4KB LDS): block = name, 256 thr = 4 waves,
// wave = word. Two-pass softmax via gathers (pass-2 re-gathers are L1-hot;
// R15 measured that caching them in LDS is NOT a win). LDS atomics to bins.
__global__ __launch_bounds__(256) void k_bins(const int* __restrict__ inputs,
                                              const int* __restrict__ nwords,
                                              const float* __restrict__ etab,
                                              float* __restrict__ Wn) {
  const int g = blockIdx.x, t = threadIdx.x;
  const int wv = t >> 6, l = t & 63;
  const int h = l & 7, qg = l >> 3;
  __shared__ float bins[VOC * NH];  // [c][h], 4 KB
  __shared__ int wred[4];
  __shared__ int sh_nwg;

  for (int i = t; i < VOC * NH; i += 256) bins[i] = 0.f;
  // in-block exclusive prefix: o0 = sum_{i<g} n_words[i], nw = n_words[g]
  int partial = 0;
  for (int i = t; i < GNAMES; i += 256) {
    int v = nwords[i];
    partial += (i < g) ? v : 0;
    if (i == g) sh_nwg = v;  // unique writer
  }
  #pragma unroll
  for (int d = 1; d < 64; d <<= 1) partial += __shfl_xor(partial, d);
  if (l == 0) wred[wv] = partial;
  __syncthreads();
  const int nw = sh_nwg;
  const int o0 = wred[0] + wred[1] + wred[2] + wred[3];

  for (int wrel = wv; wrel < nw; wrel += 4) {
    const int wi = o0 + wrel;
    int c_l = (l < LW) ? inputs[(size_t)wi * LW + l] : 0;
    unsigned long long mk = __ballot(c_l != 0);
    int cnt = __popcll(mk);
    float invc = cnt ? 1.f / (float)cnt : 0.f;

    int cq0 = __shfl(c_l, qg);
    int cq1 = __shfl(c_l, qg + 8);
    int cq2 = __shfl(c_l, qg + 16);
    const float* b0 = etab + (cq0 << 10) + h;
    const float* b1 = etab + (cq1 << 10) + h;
    const float* b2 = etab + (cq2 << 10) + h;

    // pass 1: gather rows, accumulate denominators
    float r0[LW], r1[LW], r2[LW];
    float d0 = 0.f, d1 = 0.f, d2 = 0.f;
    #pragma unroll
    for (int kp = 0; kp < LW; ++kp) {
      int o = __shfl(c_l, kp) << 3;
      r0[kp] = b0[o]; r1[kp] = b1[o]; r2[kp] = b2[o];
      d0 += r0[kp]; d1 += r1[kp]; d2 += r2[kp];
    }
    float i0 = cq0 ? invc / d0 : 0.f;
    float i1 = cq1 ? invc / d1 : 0.f;
    float i2 = cq2 ? invc / d2 : 0.f;

    // pass 2: weighting, q-reduce, scatter to char bins
    #pragma unroll
    for (int kp = 0; kp < LW; ++kp) {
      int ck = __shfl(c_l, kp);   // wave-uniform
      if (ck) {
        float v = r0[kp] * i0 + r1[kp] * i1 + r2[kp] * i2;
        v += __shfl_xor(v, 8);
        v += __shfl_xor(v, 16);
        v += __shfl_xor(v, 32);
        if (qg == 0) atomicAdd(&bins[(ck << 3) + h], v);
      }
    }
  }
  __syncthreads();

  // write Wn[g][h][c] from bins[c][h]
  const float invn = nw ? 1.f / (float)nw : 0.f;
  for (int i = t; i < NH * VOC; i += 256) {
    int hh = i >> 7, cc = i & 127;
    Wn[(size_t)g * 1024 + i] = bins[(cc << 3) + hh] * invn;
  }
}

extern "C" void kernel_launch(void* const* d_in, const int* in_sizes, int n_in,
                              void* d_out, int out_size, void* d_ws, size_t ws_size,
                              hipStream_t stream) {
  const int*   inputs  = (const int*)d_in[0];
  const int*   n_words = (const int*)d_in[1];
  const float* emb     = (const float*)d_in[3];
  const float* Wq      = (const float*)d_in[4];
  const float* Wk      = (const float*)d_in[5];
  const float* Wv      = (const float*)d_in[6];
  const float* Wo      = (const float*)d_in[7];
  const float* W1      = (const float*)d_in[8];
  const float* W2      = (const float*)d_in[9];
  float* out = (float*)d_out;

  // workspace layout (floats), ~47 MB (d_ws is 256 MB per poison-fill size)
  float* ws   = (float*)d_ws;
  float* BIG  = ws;                     // 4 x S1_LEN = 1,835,008 raw stage-1 partials
  float* TAB  = ws + 1835008;           // 131,072: exp table [c1][c2][h]
  float* EVWF = ws + 1966080;           // 327,680: reduced [EV | WF]
  float* NP   = ws + 2293760;           // 2048*512 = 1,048,576
  float* Wn   = ws + 3342336;           // 2048*1024 = 2,097,152
  float* ILVP = ws + 5439488;           // 4 x 2048*512 = 4,194,304 (interleaved)
  float* OUTP = ws + 9633792;           // 4 x 2048*256 = 2,097,152

  // 1) stage-1 fused GEMMs, split-K=4 -> 448 blocks, raw partials
  k_stage1<4><<<dim3(112, 4), 256, 0, stream>>>(emb, Wq, Wk, Wv, Wo, W1, BIG);
  // 2) exp-table tiles (sum folded) + EV/WF elementwise reduce -> EVWF
  k_qk_tab2<<<352, 256, 0, stream>>>(BIG, TAB, EVWF);
  // 3) fused offsets + histogram -> Wn
  k_bins<<<GNAMES, 256, 0, stream>>>(inputs, n_words, TAB, Wn);
  // 4) NP = per-head Wn @ EV (tiled GEMM, EV reuse through LDS)
  k_npool<<<dim3(GNAMES / 64, NH), 256, 0, stream>>>(Wn, EVWF, NP);
  // 5) NP @ WF, split-K=4 -> INTERLEAVED partials
  k_gemm_ilv<<<dim3(8, 32, 4), 256, 0, stream>>>(NP, EVWF + 65536, ILVP, 128);
  // 6) out_partials = tanh(sum interleaved partials) @ W2, split-K=4
  k_gemm_tail<<<dim3(4, 32, 4), 256, 0, stream>>>(ILVP, W2, OUTP, 128);
  // 7) out = tanh(sum out_partials)
  k_reduce<1, 4><<<(GNAMES * F2) / 4 / 256, 256, 0, stream>>>(OUTP, out, (GNAMES * F2) / 4, (GNAMES * F2) / 4);
}